// Round 15
// baseline (117.483 us; speedup 1.0000x reference)
//
#include <hip/hip_runtime.h>
#include <math.h>

#define BB 4
#define LQ 2048
#define LK 2048
#define DK 512
#define DV 512

typedef __attribute__((ext_vector_type(8))) _Float16 f16x8;
typedef __attribute__((ext_vector_type(2))) _Float16 f16x2;
typedef __attribute__((ext_vector_type(4))) float f32x4;

// ws layout (f32-element offsets)
#define WS_QW    0                  // f32[8192]
#define WS_KW    8192               // f32[8192]
#define WS_M     16384              // f32[8192]
#define WS_INV   24576              // f32[8192]
#define WS_VF16  32768              // u16 vF[8,388,608 B] = 8.4 MB
#define WS_AH    4227072            // u16 aH[33,554,432 B]
#define WS_AL    12615680           // u16 aL[33,554,432 B]
#define WS_END_EXACT 21004288       // f32 slots -> 84.0 MB
#define WS_END_HI    12615680       // 50.5 MB (known to fit: R4 split path ran)
#define NOUT     ((size_t)BB * LQ * DV)

__device__ __forceinline__ unsigned int pk2(float a, float b) {
    auto h = __builtin_amdgcn_cvt_pkrtz(a, b);   // __fp16 ext_vector(2), RTZ
    return __builtin_bit_cast(unsigned int, h);
}

// ---------------------------------------------------------------------------
// A: qw/kw — one wave per row.
// ---------------------------------------------------------------------------
__global__ __launch_bounds__(256) void qkw_kernel(const float* __restrict__ q,
                                                  const float* __restrict__ k,
                                                  const float* __restrict__ w,
                                                  float* __restrict__ ws) {
    int gw   = (int)((blockIdx.x * blockDim.x + threadIdx.x) >> 6);
    int lane = threadIdx.x & 63;
    const int nq = BB * LQ;
    const float* row = (gw < nq) ? (q + (size_t)gw * DK) : (k + (size_t)(gw - nq) * DK);

    float acc = 0.f;
#pragma unroll
    for (int j = 0; j < DK; j += 256) {
        int idx = j + lane * 4;
        float4 rv = *reinterpret_cast<const float4*>(row + idx);
        float4 wv = *reinterpret_cast<const float4*>(w + idx);
        acc += rv.x * wv.x + rv.y * wv.y + rv.z * wv.z + rv.w * wv.w;
    }
#pragma unroll
    for (int off = 32; off >= 1; off >>= 1) acc += __shfl_xor(acc, off, 64);
    if (lane == 0) ws[gw] = acc;
}

// ---------------------------------------------------------------------------
// C: v -> MFMA-fragment-ordered fp16 (RTN).
// vF u16 index: (((b*32 + n16)*64 + k32)*64 + lane)*8 + j
// ---------------------------------------------------------------------------
__global__ __launch_bounds__(256) void vpack_kernel(const float* __restrict__ v,
                                                    unsigned short* __restrict__ vF) {
    __shared__ float tile[32][517];
    const int k32 = blockIdx.x;
    const int b   = blockIdx.y;
    const int k0  = k32 * 32;
    const int t   = threadIdx.x;

#pragma unroll
    for (int i = 0; i < 16; ++i) {
        int flat = i * 256 + t;
        int row  = flat >> 7;
        int c4   = flat & 127;
        float4 f = *reinterpret_cast<const float4*>(
            v + ((size_t)(b * LK + k0 + row)) * DV + c4 * 4);
        tile[row][c4 * 4 + 0] = f.x;
        tile[row][c4 * 4 + 1] = f.y;
        tile[row][c4 * 4 + 2] = f.z;
        tile[row][c4 * 4 + 3] = f.w;
    }
    __syncthreads();

    const int w = t >> 6, l = t & 63;
    const int rbase = (l >> 4) * 8;
#pragma unroll
    for (int f = 0; f < 8; ++f) {
        int n16 = w * 8 + f;
        int col = n16 * 16 + (l & 15);
        f16x8 vv;
#pragma unroll
        for (int j = 0; j < 8; ++j) vv[j] = (_Float16)tile[rbase + j][col];
        size_t u16base = (((size_t)(b * 32 + n16)) * 64 + k32) * 512;
        *reinterpret_cast<f16x8*>(vF + u16base + l * 8) = vv;
    }
}

// ---------------------------------------------------------------------------
// B1: per-row masked softmax stats + attn f32 write + FRAGMENT-ORDERED fp16
// split of p into aH (+ aL if writeL). Fragment dest for element k of row rid:
//   unit = rid>>6, mf = (rid>>4)&3, r16 = rid&15
//   u16 idx = unit*131072 + mf*512 + r16*8 + (k>>5)*2048 + ((k>>3)&3)*128 + (k&7)
// ---------------------------------------------------------------------------
__global__ __launch_bounds__(256) void rowstat_kernel(const int* __restrict__ mask,
                                                      float* __restrict__ ws,
                                                      float* __restrict__ attn,
                                                      unsigned short* __restrict__ aH,
                                                      unsigned short* __restrict__ aL,
                                                      int writeL) {
    __shared__ float kws[LK];
    const int b = (blockIdx.x * 4) / LQ;
    const int t = threadIdx.x;

    const float4* kw4 = reinterpret_cast<const float4*>(ws + WS_KW + b * LK);
#pragma unroll
    for (int i = 0; i < 2; ++i)
        reinterpret_cast<float4*>(kws)[t + i * 256] = kw4[t + i * 256];
    __syncthreads();

    const int wave = t >> 6, lane = t & 63;
    const int rid  = blockIdx.x * 4 + wave;
    const float qwv = ws[WS_QW + rid];
    const int* mrow = mask + (size_t)rid * LK;

    float m = -INFINITY, s = 0.f;
    unsigned int mybits = 0;
#pragma unroll
    for (int i = 0; i < 8; ++i) {
        int e = (i * 64 + lane) * 4;
        int4  mi = *reinterpret_cast<const int4*>(mrow + e);
        float4 kv = reinterpret_cast<const float4*>(kws)[i * 64 + lane];
        float vals[4] = {kv.x, kv.y, kv.z, kv.w};
        int   msks[4] = {mi.x, mi.y, mi.z, mi.w};

        unsigned int bits = (msks[0] ? 1u : 0u) | (msks[1] ? 2u : 0u) |
                            (msks[2] ? 4u : 0u) | (msks[3] ? 8u : 0u);
        mybits |= bits << (i * 4);

#pragma unroll
        for (int j = 0; j < 4; ++j) {
            float sc = qwv - vals[j];
            sc = fmaxf(sc, 0.01f * sc);
            if (msks[j]) {
                if (sc > m) { s = s * __expf(m - sc) + 1.f; m = sc; }
                else        { s += __expf(sc - m); }
            }
        }
    }
#pragma unroll
    for (int off = 32; off >= 1; off >>= 1) {
        float mo = __shfl_xor(m, off, 64);
        float so = __shfl_xor(s, off, 64);
        float M  = fmaxf(m, mo);
        float sa = (m  == M) ? s  : s  * __expf(m  - M);
        float sb = (mo == M) ? so : so * __expf(mo - M);
        m = M; s = sa + sb;
    }
    const float inv = (s > 0.f) ? 1.f / s : 0.f;
    if (lane == 0) {
        ws[WS_M   + rid] = m;
        ws[WS_INV + rid] = inv;
    }

    // ---- pass 2: exact p -> attn f32 (coalesced) + fragment fp16 split ----
    float* arow = attn + (size_t)rid * LK;
    const int unit = rid >> 6;
    const size_t rowbase = (size_t)unit * 131072 + ((rid >> 4) & 3) * 512 + (rid & 15) * 8;
#pragma unroll
    for (int i = 0; i < 8; ++i) {
        float4 kv = reinterpret_cast<const float4*>(kws)[i * 64 + lane];
        float vals[4] = {kv.x, kv.y, kv.z, kv.w};
        unsigned int bits = (mybits >> (i * 4)) & 0xFu;
        float p[4];
#pragma unroll
        for (int j = 0; j < 4; ++j) {
            float sc = qwv - vals[j];
            sc = fmaxf(sc, 0.01f * sc);
            p[j] = (bits & (1u << j)) ? __expf(sc - m) * inv : 0.f;
        }
        const int k4 = (i * 64 + lane) * 4;
        *reinterpret_cast<float4*>(arow + k4) = make_float4(p[0], p[1], p[2], p[3]);

        const size_t fdest = rowbase + (size_t)(k4 >> 5) * 2048 +
                             ((k4 >> 3) & 3) * 128 + (k4 & 7);
        if (writeL) {
            unsigned int h01 = pk2(p[0], p[1]);
            unsigned int h23 = pk2(p[2], p[3]);
            f16x2 a2 = __builtin_bit_cast(f16x2, h01);
            f16x2 b2 = __builtin_bit_cast(f16x2, h23);
            unsigned int l01 = pk2(p[0] - (float)a2[0], p[1] - (float)a2[1]);
            unsigned int l23 = pk2(p[2] - (float)b2[0], p[3] - (float)b2[1]);
            *reinterpret_cast<uint2*>(aH + fdest) = make_uint2(h01, h23);
            *reinterpret_cast<uint2*>(aL + fdest) = make_uint2(l01, l23);
        } else {
            // RTN hi-only (tighter rounding when no residual term)
            f16x2 h0, h1;
            h0[0] = (_Float16)p[0]; h0[1] = (_Float16)p[1];
            h1[0] = (_Float16)p[2]; h1[1] = (_Float16)p[3];
            *reinterpret_cast<uint2*>(aH + fdest) =
                make_uint2(__builtin_bit_cast(unsigned int, h0),
                           __builtin_bit_cast(unsigned int, h1));
        }
    }
}

// ---------------------------------------------------------------------------
// B2: pure-register streaming PV. NO LDS, NO barriers, NO conversion.
// Block = 64 q-rows x 128 n-cols x full K. 256 thr (4 waves); wave owns 2 nb.
// Per step: load A fragments (aH[,aL]) + B fragments (vF) from L1/L2, 16 MFMA.
// XCD-COLOCATED decode (R12-verified). 512 blocks = 2/CU; waves free-run.
// ---------------------------------------------------------------------------
template <int TERMS>
__global__ __launch_bounds__(256, 2) void pv_kernel(
        const unsigned short* __restrict__ aH,
        const unsigned short* __restrict__ aL,
        const unsigned short* __restrict__ vF,
        float* __restrict__ out) {
    const int bid  = blockIdx.x;
    const int xcd  = bid & 7;
    const int rest = bid >> 3;
    const int g    = rest >> 2;
    const int ns   = rest & 3;
    const int qt4b = g * 8 + xcd;          // qt*4 + b
    const int b    = qt4b & 3;
    const int qt   = qt4b >> 2;
    const int ksteps = LK >> 5;            // 64

    const int t = threadIdx.x;
    const int w = t >> 6, l = t & 63;
    const int unit = b * 32 + qt;

    // A fragment bases (u16): + s*2048 per step
    const unsigned short* ah = aH + (size_t)unit * 131072 + (size_t)l * 8;
    const unsigned short* al = aL + (size_t)unit * 131072 + (size_t)l * 8;

    // B fragment bases: wave w owns n16 = ns*8 + w*2 + nb; + s*512 per step
    const unsigned short* bsrc[2];
#pragma unroll
    for (int nb = 0; nb < 2; ++nb)
        bsrc[nb] = vF + (((size_t)(b * 32 + ns * 8 + w * 2 + nb)) * 64) * 512
                      + (size_t)l * 8;

    // prologue: load step 0
    f16x8 aHc[4], aLc[4], bC[2], aHn[4], aLn[4], bN[2];
#pragma unroll
    for (int mf = 0; mf < 4; ++mf) {
        aHc[mf] = *reinterpret_cast<const f16x8*>(ah + mf * 512);
        if (TERMS == 2) aLc[mf] = *reinterpret_cast<const f16x8*>(al + mf * 512);
    }
#pragma unroll
    for (int nb = 0; nb < 2; ++nb)
        bC[nb] = *reinterpret_cast<const f16x8*>(bsrc[nb]);

    f32x4 acc[4][2];
#pragma unroll
    for (int mf = 0; mf < 4; ++mf)
#pragma unroll
        for (int nb = 0; nb < 2; ++nb)
            acc[mf][nb] = (f32x4){0.f, 0.f, 0.f, 0.f};

    for (int s = 0; s < ksteps; ++s) {
        const int sn = (s + 1 < ksteps) ? s + 1 : s;

        // prefetch next step (no barriers -> loads pipeline freely)
#pragma unroll
        for (int mf = 0; mf < 4; ++mf) {
            aHn[mf] = *reinterpret_cast<const f16x8*>(ah + (size_t)sn * 2048 + mf * 512);
            if (TERMS == 2)
                aLn[mf] = *reinterpret_cast<const f16x8*>(al + (size_t)sn * 2048 + mf * 512);
        }
#pragma unroll
        for (int nb = 0; nb < 2; ++nb)
            bN[nb] = *reinterpret_cast<const f16x8*>(bsrc[nb] + (size_t)sn * 512);

        // MFMA cluster
#pragma unroll
        for (int nb = 0; nb < 2; ++nb)
#pragma unroll
            for (int mf = 0; mf < 4; ++mf) {
                acc[mf][nb] = __builtin_amdgcn_mfma_f32_16x16x32_f16(aHc[mf], bC[nb], acc[mf][nb], 0, 0, 0);
                if (TERMS == 2)
                    acc[mf][nb] = __builtin_amdgcn_mfma_f32_16x16x32_f16(aLc[mf], bC[nb], acc[mf][nb], 0, 0, 0);
            }

#pragma unroll
        for (int mf = 0; mf < 4; ++mf) { aHc[mf] = aHn[mf]; if (TERMS == 2) aLc[mf] = aLn[mf]; }
#pragma unroll
        for (int nb = 0; nb < 2; ++nb) bC[nb] = bN[nb];
    }

    // epilogue: col = ns*128 + (w*2+nb)*16 + (l&15), row = qt*64 + mf*16 + (l>>4)*4 + r
    float* obase = out + ((size_t)(b * LQ + qt * 64)) * DV
                       + ns * 128 + w * 32 + (l & 15);
#pragma unroll
    for (int mf = 0; mf < 4; ++mf)
#pragma unroll
        for (int nb = 0; nb < 2; ++nb)
#pragma unroll
            for (int r = 0; r < 4; ++r)
                obase[(size_t)(mf * 16 + (l >> 4) * 4 + r) * DV + nb * 16] = acc[mf][nb][r];
}

// ---------------------------------------------------------------------------
extern "C" void kernel_launch(void* const* d_in, const int* in_sizes, int n_in,
                              void* d_out, int out_size, void* d_ws, size_t ws_size,
                              hipStream_t stream) {
    const float* q    = (const float*)d_in[0];
    const float* k    = (const float*)d_in[1];
    const float* v    = (const float*)d_in[2];
    const int*   mask = (const int*)d_in[3];
    const float* w    = (const float*)d_in[4];

    float* out  = (float*)d_out;                       // [B, LQ, DV]
    float* attn = out + NOUT;                          // [B, LQ, LK]
    float* ws   = (float*)d_ws;

    unsigned short* vF = (unsigned short*)(ws + WS_VF16);
    unsigned short* aH = (unsigned short*)(ws + WS_AH);
    unsigned short* aL = (unsigned short*)(ws + WS_AL);

    const bool exact = ws_size >= (size_t)WS_END_EXACT * 4;

    qkw_kernel<<<4096, 256, 0, stream>>>(q, k, w, ws);
    vpack_kernel<<<dim3(64, 4), 256, 0, stream>>>(v, vF);
    rowstat_kernel<<<2048, 256, 0, stream>>>(mask, ws, attn, aH, aL, exact ? 1 : 0);

    if (exact)
        pv_kernel<2><<<512, 256, 0, stream>>>(aH, aL, vF, out);
    else
        pv_kernel<1><<<512, 256, 0, stream>>>(aH, aL, vF, out);
}